// Round 6
// baseline (135.351 us; speedup 1.0000x reference)
//
#include <hip/hip_runtime.h>
#include <math.h>

#define D 3072
#define BATCH 512
#define NCLS 100
#define NPAD 112
#define KS 32
#define KCHUNK (D / KS)   // 96

typedef __attribute__((ext_vector_type(8))) short bf16x8;
typedef __attribute__((ext_vector_type(4))) float f32x4;

// ws byte layout (fast path):
//   0       : A colsum (3072 f32) + B colsum (3072 f32)   24576 B
//   24576   : Wb bf16 [112][3072]                          688128 B
#define WS_OFF_W   24576
#define WS_NEED    (WS_OFF_W + (size_t)NPAD * D * 2)

__device__ inline unsigned short f2bf(float f) {
    unsigned u = __float_as_uint(f);
    u += 0x7FFF + ((u >> 16) & 1);          // round-to-nearest-even
    return (unsigned short)(u >> 16);
}

// ---------------------------------------------------------------------------
// K1 "prep": three independent jobs in one dispatch:
//  blocks [0,288):   colsum  A[d]=sum_i a[i*D+d], B[d]=sum_i b[i*D+d]
//                    (96 row-chunks x 3 col-groups, float4, atomics: 96/addr)
//  blocks [288,624): fc_w fp32 [100][3072] -> bf16 [112][3072] (pad rows 0)
//  blocks [624,674): zero d_out (51200 f32) so K2 can atomically accumulate
//                    (visible to K2 via stream serialization)
// ---------------------------------------------------------------------------
__global__ __launch_bounds__(256) void prep_kernel(const float* __restrict__ a,
                                                   const float* __restrict__ b,
                                                   const float* __restrict__ fcw,
                                                   float* __restrict__ ws,
                                                   unsigned short* __restrict__ Wb,
                                                   float* __restrict__ out) {
    const int bid = blockIdx.x;
    const int t   = threadIdx.x;
    if (bid < 288) {
        const int rc   = bid / 3;
        const int cg   = bid % 3;
        const int col  = cg * 1024 + t * 4;
        const int row0 = rc * 32;
        float4 sa = make_float4(0.f, 0.f, 0.f, 0.f);
        float4 sb = make_float4(0.f, 0.f, 0.f, 0.f);
        #pragma unroll
        for (int r = 0; r < 32; ++r) {
            const int i = row0 + r;
            const float4 va = *(const float4*)(a + i * D + col);
            const float4 vb = *(const float4*)(b + i * D + col);
            sa.x += va.x; sa.y += va.y; sa.z += va.z; sa.w += va.w;
            sb.x += vb.x; sb.y += vb.y; sb.z += vb.z; sb.w += vb.w;
        }
        atomicAdd(&ws[col + 0], sa.x);
        atomicAdd(&ws[col + 1], sa.y);
        atomicAdd(&ws[col + 2], sa.z);
        atomicAdd(&ws[col + 3], sa.w);
        atomicAdd(&ws[D + col + 0], sb.x);
        atomicAdd(&ws[D + col + 1], sb.y);
        atomicAdd(&ws[D + col + 2], sb.z);
        atomicAdd(&ws[D + col + 3], sb.w);
    } else if (bid < 624) {
        const int idx = (bid - 288) * 256 + t;     // 0..86015
        const int c   = idx / (D / 4);
        const int d   = (idx % (D / 4)) * 4;
        ushort4 o;
        if (c < NCLS) {
            const float4 v = *(const float4*)(fcw + c * D + d);
            o.x = f2bf(v.x); o.y = f2bf(v.y); o.z = f2bf(v.z); o.w = f2bf(v.w);
        } else {
            o.x = o.y = o.z = o.w = 0;
        }
        *(ushort4*)(Wb + c * D + d) = o;
    } else {
        const int idx = (bid - 624) * 256 + t;     // 0..12799
        *(float4*)(out + idx * 4) = make_float4(0.f, 0.f, 0.f, 0.f);
    }
}

// ---------------------------------------------------------------------------
// K2 "fzgemm": fused Z-gen + MFMA GEMM, split-K accumulated atomically into
// d_out (zeroed by prep; bias folded in by j==0 blocks).
//   Z[b,d] = part1 + cos(x)*A[d] + sin(x)*B[d]  computed on the fly into the
//   A-fragment (each Z element feeds exactly ONE fragment -> zero redundancy),
//   then out += Z_chunk x Wb^T  via 16x16x32 bf16 MFMA.
// Grid (8 m-blocks, KS=32 k-chunks) x 256 = 256 blocks (1/CU).
// A/B frag: lane = row/col (lane&15), k = (lane>>4)*8 + j.
// C/D:      col = lane&15, row = (lane>>4)*4 + reg   [verified R4].
// ---------------------------------------------------------------------------
__global__ __launch_bounds__(256) void fzgemm_kernel(
        const float* __restrict__ x,
        const float* __restrict__ w5,
        const float* __restrict__ n5,
        const float* __restrict__ ws,               // A=ws[0:D], B=ws[D:2D]
        const unsigned short* __restrict__ Wb,      // [112][3072] bf16
        const float* __restrict__ fcb,
        float* __restrict__ out) {                  // [512][100], pre-zeroed
    const int wave = threadIdx.x >> 6;
    const int lane = threadIdx.x & 63;
    const int l16  = lane & 15;
    const int quad = lane >> 4;
    const int m0   = blockIdx.x * 64 + wave * 16;   // m-tile base (16 rows)
    const int j    = blockIdx.y;                    // k-chunk
    const int kb   = j * KCHUNK + quad * 8;         // this lane's k base

    float part1 = 0.f;
    #pragma unroll
    for (int i = 0; i < 4; ++i)
        part1 += w5[i + 1] * n5[i + 1] + w5[i] * n5[i];

    f32x4 acc[7];
    #pragma unroll
    for (int n = 0; n < 7; ++n) acc[n] = (f32x4){0.f, 0.f, 0.f, 0.f};

    const float* xr = x + (m0 + l16) * D;           // this lane's x row

    #pragma unroll
    for (int kk = 0; kk < KCHUNK; kk += 32) {
        const int col = kb + kk;
        const float4 xv0 = *(const float4*)(xr + col);
        const float4 xv1 = *(const float4*)(xr + col + 4);
        const float4 Av0 = *(const float4*)(ws + col);
        const float4 Av1 = *(const float4*)(ws + col + 4);
        const float4 Bv0 = *(const float4*)(ws + D + col);
        const float4 Bv1 = *(const float4*)(ws + D + col + 4);

        union { bf16x8 v; unsigned short s[8]; } af;
        float sv, cv;
        __sincosf(xv0.x, &sv, &cv); af.s[0] = f2bf(part1 + cv * Av0.x + sv * Bv0.x);
        __sincosf(xv0.y, &sv, &cv); af.s[1] = f2bf(part1 + cv * Av0.y + sv * Bv0.y);
        __sincosf(xv0.z, &sv, &cv); af.s[2] = f2bf(part1 + cv * Av0.z + sv * Bv0.z);
        __sincosf(xv0.w, &sv, &cv); af.s[3] = f2bf(part1 + cv * Av0.w + sv * Bv0.w);
        __sincosf(xv1.x, &sv, &cv); af.s[4] = f2bf(part1 + cv * Av1.x + sv * Bv1.x);
        __sincosf(xv1.y, &sv, &cv); af.s[5] = f2bf(part1 + cv * Av1.y + sv * Bv1.y);
        __sincosf(xv1.z, &sv, &cv); af.s[6] = f2bf(part1 + cv * Av1.z + sv * Bv1.z);
        __sincosf(xv1.w, &sv, &cv); af.s[7] = f2bf(part1 + cv * Av1.w + sv * Bv1.w);

        #pragma unroll
        for (int n = 0; n < 7; ++n) {
            const bf16x8 bf = *(const bf16x8*)(Wb + (n * 16 + l16) * D + col);
            acc[n] = __builtin_amdgcn_mfma_f32_16x16x32_bf16(af.v, bf, acc[n], 0, 0, 0);
        }
    }

    #pragma unroll
    for (int n = 0; n < 7; ++n) {
        const int c = n * 16 + l16;
        if (c < NCLS) {
            #pragma unroll
            for (int r = 0; r < 4; ++r) {
                float v = acc[n][r];
                if (j == 0 && quad == 0 && r == 0) { /* placeholder keep shape */ }
                atomicAdd(&out[(m0 + quad * 4 + r) * NCLS + c],
                          v + ((j == 0 && quad == 0 && r == 0) ? 0.f : 0.f));
            }
        }
    }
    // bias: added exactly once per (row,c) by the j==0 blocks' quad0/r loop
    // being insufficient (each row handled by one (quad,r) pair) -> instead
    // fold bias here: j==0 contributes fcb once per row,c.
    if (j == 0) {
        #pragma unroll
        for (int n = 0; n < 7; ++n) {
            const int c = n * 16 + l16;
            if (c < NCLS) {
                #pragma unroll
                for (int r = 0; r < 4; ++r) {
                    // each (row,c) belongs to exactly one lane (quad,r,l16) in
                    // exactly one j==0 block -> add bias exactly once
                    if (r == 0 && quad >= 0) {} // no-op
                }
                // one add per (row,c): do it for all 4 rows this lane owns
                #pragma unroll
                for (int r = 0; r < 4; ++r)
                    atomicAdd(&out[(m0 + quad * 4 + r) * NCLS + c], fcb[c]);
            }
        }
    }
}

// ---------------------------------------------------------------------------
// Fallback (R3's verified path) if ws_size < WS_NEED (insurance only).
// ---------------------------------------------------------------------------
__global__ __launch_bounds__(256) void fused_gemm_kernel(
        const float* __restrict__ x,
        const float* __restrict__ w5,
        const float* __restrict__ n5,
        const float* __restrict__ fcw,
        const float* __restrict__ fcb,
        const float* __restrict__ ws,
        float* __restrict__ out) {
    __shared__ __align__(16) float Zl[32 * 36];
    __shared__ __align__(16) float Wl[32 * 132];
    const int t  = threadIdx.x;
    const int bt = blockIdx.x;
    const int j  = blockIdx.y;
    float part1 = 0.f;
    #pragma unroll
    for (int i = 0; i < 4; ++i)
        part1 += w5[i + 1] * n5[i + 1] + w5[i] * n5[i];
    const int c0 = (t & 31) * 4;
    const int b0 = (t >> 5) * 4;
    const int kl = t & 31;
    const int tg = t >> 5;
    const int bbase = bt * 32;
    float acc[4][4];
    #pragma unroll
    for (int i = 0; i < 4; ++i)
        #pragma unroll
        for (int q = 0; q < 4; ++q) acc[i][q] = 0.f;
    for (int s = 0; s < 3; ++s) {
        const int dbase = j * 96 + s * 32;
        for (int idx = t; idx < NCLS * 32; idx += 256) {
            const int c = idx >> 5;
            const int k = idx & 31;
            Wl[k * 132 + c] = fcw[c * D + dbase + k];
        }
        const float Av = ws[dbase + kl];
        const float Bv = ws[D + dbase + kl];
        #pragma unroll
        for (int i = 0; i < 4; ++i) {
            const int bl = tg + i * 8;
            const float xv = x[(bbase + bl) * D + dbase + kl];
            float sv, cv;
            sincosf(xv, &sv, &cv);
            Zl[bl * 36 + kl] = part1 + cv * Av + sv * Bv;
        }
        __syncthreads();
        #pragma unroll
        for (int k = 0; k < 32; ++k) {
            const float4 wv = *(const float4*)&Wl[k * 132 + c0];
            float zb[4];
            #pragma unroll
            for (int bj = 0; bj < 4; ++bj) zb[bj] = Zl[(b0 + bj) * 36 + k];
            #pragma unroll
            for (int bj = 0; bj < 4; ++bj) {
                acc[bj][0] += zb[bj] * wv.x;
                acc[bj][1] += zb[bj] * wv.y;
                acc[bj][2] += zb[bj] * wv.z;
                acc[bj][3] += zb[bj] * wv.w;
            }
        }
        __syncthreads();
    }
    if (c0 < NCLS) {
        #pragma unroll
        for (int bj = 0; bj < 4; ++bj) {
            const int row = bbase + b0 + bj;
            #pragma unroll
            for (int q = 0; q < 4; ++q) {
                const int c = c0 + q;
                if (c < NCLS) {
                    float v = acc[bj][q];
                    if (j == 0) v += fcb[c];
                    atomicAdd(&out[row * NCLS + c], v);
                }
            }
        }
    }
}

extern "C" void kernel_launch(void* const* d_in, const int* in_sizes, int n_in,
                              void* d_out, int out_size, void* d_ws, size_t ws_size,
                              hipStream_t stream) {
    const float* x   = (const float*)d_in[0];
    const float* a   = (const float*)d_in[1];
    const float* b   = (const float*)d_in[2];
    const float* w5  = (const float*)d_in[3];
    const float* n5  = (const float*)d_in[4];
    const float* fcw = (const float*)d_in[5];
    const float* fcb = (const float*)d_in[6];
    float* out = (float*)d_out;
    float* wsf = (float*)d_ws;

    hipMemsetAsync(d_ws, 0, 2 * D * sizeof(float), stream);

    if (ws_size >= WS_NEED) {
        unsigned short* Wb = (unsigned short*)((char*)d_ws + WS_OFF_W);
        prep_kernel<<<dim3(674), 256, 0, stream>>>(a, b, fcw, wsf, Wb, out);
        fzgemm_kernel<<<dim3(8, KS), 256, 0, stream>>>(x, w5, n5, wsf, Wb, fcb, out);
    } else {
        hipMemsetAsync(d_out, 0, (size_t)out_size * sizeof(float), stream);
        prep_kernel<<<dim3(288), 256, 0, stream>>>(a, b, fcw, wsf,
                                                   (unsigned short*)d_ws /*unused*/,
                                                   out);
        fused_gemm_kernel<<<dim3(16, 32), 256, 0, stream>>>(x, w5, n5, fcw, fcb,
                                                            wsf, out);
    }
}

// Round 7
// 128.153 us; speedup vs baseline: 1.0562x; 1.0562x over previous
//
#include <hip/hip_runtime.h>
#include <math.h>

#define D 3072
#define BATCH 512
#define NCLS 100
#define KS 32
#define KCHUNK (D / KS)   // 96

typedef __attribute__((ext_vector_type(8))) short bf16x8;
typedef __attribute__((ext_vector_type(4))) float f32x4;

// ws byte layout (fast path):
//   0       : A colsum (3072 f32) + B colsum (3072 f32)   24576 B
//   24576   : Wb bf16 [112][3072]                          688128 B
//   712704  : partials [KS][512][100] f32                  6553600 B
#define WS_OFF_W   24576
#define WS_OFF_P   712704
#define WS_NEED    (WS_OFF_P + (size_t)KS * BATCH * NCLS * 4)

__device__ inline unsigned short f2bf(float f) {
    unsigned u = __float_as_uint(f);
    u += 0x7FFF + ((u >> 16) & 1);          // round-to-nearest-even
    return (unsigned short)(u >> 16);
}

// ---------------------------------------------------------------------------
// K1 "prep": two independent jobs in one dispatch:
//  blocks [0,288):   colsum  A[d]=sum_i a[i*D+d], B[d]=sum_i b[i*D+d]
//                    (96 row-chunks x 3 col-groups, float4, atomics: 96/addr)
//  blocks [288,624): fc_w fp32 [100][3072] -> bf16 [112][3072] (pad rows 0)
// ---------------------------------------------------------------------------
__global__ __launch_bounds__(256) void prep_kernel(const float* __restrict__ a,
                                                   const float* __restrict__ b,
                                                   const float* __restrict__ fcw,
                                                   float* __restrict__ ws,
                                                   unsigned short* __restrict__ Wb) {
    const int bid = blockIdx.x;
    const int t   = threadIdx.x;
    if (bid < 288) {
        const int rc   = bid / 3;
        const int cg   = bid % 3;
        const int col  = cg * 1024 + t * 4;
        const int row0 = rc * 32;
        float4 sa = make_float4(0.f, 0.f, 0.f, 0.f);
        float4 sb = make_float4(0.f, 0.f, 0.f, 0.f);
        #pragma unroll
        for (int r = 0; r < 32; ++r) {
            const int i = row0 + r;
            const float4 va = *(const float4*)(a + i * D + col);
            const float4 vb = *(const float4*)(b + i * D + col);
            sa.x += va.x; sa.y += va.y; sa.z += va.z; sa.w += va.w;
            sb.x += vb.x; sb.y += vb.y; sb.z += vb.z; sb.w += vb.w;
        }
        atomicAdd(&ws[col + 0], sa.x);
        atomicAdd(&ws[col + 1], sa.y);
        atomicAdd(&ws[col + 2], sa.z);
        atomicAdd(&ws[col + 3], sa.w);
        atomicAdd(&ws[D + col + 0], sb.x);
        atomicAdd(&ws[D + col + 1], sb.y);
        atomicAdd(&ws[D + col + 2], sb.z);
        atomicAdd(&ws[D + col + 3], sb.w);
    } else {
        const int idx = (bid - 288) * 256 + t;     // 0..86015
        const int c   = idx / (D / 4);
        const int d   = (idx % (D / 4)) * 4;
        ushort4 o;
        if (c < NCLS) {
            const float4 v = *(const float4*)(fcw + c * D + d);
            o.x = f2bf(v.x); o.y = f2bf(v.y); o.z = f2bf(v.z); o.w = f2bf(v.w);
        } else {
            o.x = o.y = o.z = o.w = 0;
        }
        *(ushort4*)(Wb + c * D + d) = o;
    }
}

// ---------------------------------------------------------------------------
// K2 "fzgemm": fused Z-gen + MFMA GEMM, split-K, deterministic partials.
//   Z[b,d] = part1 + cos(x)*A[d] + sin(x)*B[d]  computed on the fly into the
//   A-fragment (each Z element feeds exactly ONE fragment -> zero redundancy),
//   then partial[j] = Z_chunk x Wb^T  via 16x16x32 bf16 MFMA.
// Grid (8 m-blocks, KS=32 k-chunks) x 256 = 256 blocks (1/CU).
// A/B frag: lane = row/col (lane&15), k = (lane>>4)*8 + j.
// C/D:      col = lane&15, row = (lane>>4)*4 + reg   [verified R4].
// Partials stored with stride NCLS (dead cols >=100 skipped).
// ---------------------------------------------------------------------------
__global__ __launch_bounds__(256) void fzgemm_kernel(
        const float* __restrict__ x,
        const float* __restrict__ w5,
        const float* __restrict__ n5,
        const float* __restrict__ ws,               // A=ws[0:D], B=ws[D:2D]
        const unsigned short* __restrict__ Wb,      // [112][3072] bf16
        float* __restrict__ part) {                 // [KS][512][100]
    const int wave = threadIdx.x >> 6;
    const int lane = threadIdx.x & 63;
    const int l16  = lane & 15;
    const int quad = lane >> 4;
    const int m0   = blockIdx.x * 64 + wave * 16;   // m-tile base (16 rows)
    const int j    = blockIdx.y;                    // k-chunk
    const int kb   = j * KCHUNK + quad * 8;         // this lane's k base

    float part1 = 0.f;
    #pragma unroll
    for (int i = 0; i < 4; ++i)
        part1 += w5[i + 1] * n5[i + 1] + w5[i] * n5[i];

    f32x4 acc[7];
    #pragma unroll
    for (int n = 0; n < 7; ++n) acc[n] = (f32x4){0.f, 0.f, 0.f, 0.f};

    const float* xr = x + (m0 + l16) * D;           // this lane's x row

    #pragma unroll
    for (int kk = 0; kk < KCHUNK; kk += 32) {
        const int col = kb + kk;
        const float4 xv0 = *(const float4*)(xr + col);
        const float4 xv1 = *(const float4*)(xr + col + 4);
        const float4 Av0 = *(const float4*)(ws + col);
        const float4 Av1 = *(const float4*)(ws + col + 4);
        const float4 Bv0 = *(const float4*)(ws + D + col);
        const float4 Bv1 = *(const float4*)(ws + D + col + 4);

        union { bf16x8 v; unsigned short s[8]; } af;
        float sv, cv;
        __sincosf(xv0.x, &sv, &cv); af.s[0] = f2bf(part1 + cv * Av0.x + sv * Bv0.x);
        __sincosf(xv0.y, &sv, &cv); af.s[1] = f2bf(part1 + cv * Av0.y + sv * Bv0.y);
        __sincosf(xv0.z, &sv, &cv); af.s[2] = f2bf(part1 + cv * Av0.z + sv * Bv0.z);
        __sincosf(xv0.w, &sv, &cv); af.s[3] = f2bf(part1 + cv * Av0.w + sv * Bv0.w);
        __sincosf(xv1.x, &sv, &cv); af.s[4] = f2bf(part1 + cv * Av1.x + sv * Bv1.x);
        __sincosf(xv1.y, &sv, &cv); af.s[5] = f2bf(part1 + cv * Av1.y + sv * Bv1.y);
        __sincosf(xv1.z, &sv, &cv); af.s[6] = f2bf(part1 + cv * Av1.z + sv * Bv1.z);
        __sincosf(xv1.w, &sv, &cv); af.s[7] = f2bf(part1 + cv * Av1.w + sv * Bv1.w);

        #pragma unroll
        for (int n = 0; n < 7; ++n) {
            const bf16x8 bf = *(const bf16x8*)(Wb + (n * 16 + l16) * D + col);
            acc[n] = __builtin_amdgcn_mfma_f32_16x16x32_bf16(af.v, bf, acc[n], 0, 0, 0);
        }
    }

    float* pb = part + (size_t)j * (BATCH * NCLS);
    #pragma unroll
    for (int n = 0; n < 7; ++n) {
        const int c = n * 16 + l16;
        if (c < NCLS) {
            #pragma unroll
            for (int r = 0; r < 4; ++r)
                pb[(m0 + quad * 4 + r) * NCLS + c] = acc[n][r];
        }
    }
}

// ---------------------------------------------------------------------------
// K3: out[b,c] = fcb[c] + sum_ks part[ks][b][c]
// ---------------------------------------------------------------------------
__global__ __launch_bounds__(256) void reduce2_kernel(const float* __restrict__ part,
                                                      const float* __restrict__ fcb,
                                                      float* __restrict__ out) {
    const int idx = blockIdx.x * 256 + threadIdx.x;
    if (idx >= BATCH * NCLS) return;
    const int c = idx % NCLS;
    float s = fcb[c];
    #pragma unroll
    for (int ks = 0; ks < KS; ++ks)
        s += part[ks * (BATCH * NCLS) + idx];
    out[idx] = s;
}

// ---------------------------------------------------------------------------
// Fallback (R3's verified path) if ws_size < WS_NEED (insurance only).
// ---------------------------------------------------------------------------
__global__ __launch_bounds__(256) void fused_gemm_kernel(
        const float* __restrict__ x,
        const float* __restrict__ w5,
        const float* __restrict__ n5,
        const float* __restrict__ fcw,
        const float* __restrict__ fcb,
        const float* __restrict__ ws,
        float* __restrict__ out) {
    __shared__ __align__(16) float Zl[32 * 36];
    __shared__ __align__(16) float Wl[32 * 132];
    const int t  = threadIdx.x;
    const int bt = blockIdx.x;
    const int j  = blockIdx.y;
    float part1 = 0.f;
    #pragma unroll
    for (int i = 0; i < 4; ++i)
        part1 += w5[i + 1] * n5[i + 1] + w5[i] * n5[i];
    const int c0 = (t & 31) * 4;
    const int b0 = (t >> 5) * 4;
    const int kl = t & 31;
    const int tg = t >> 5;
    const int bbase = bt * 32;
    float acc[4][4];
    #pragma unroll
    for (int i = 0; i < 4; ++i)
        #pragma unroll
        for (int q = 0; q < 4; ++q) acc[i][q] = 0.f;
    for (int s = 0; s < 3; ++s) {
        const int dbase = j * 96 + s * 32;
        for (int idx = t; idx < NCLS * 32; idx += 256) {
            const int c = idx >> 5;
            const int k = idx & 31;
            Wl[k * 132 + c] = fcw[c * D + dbase + k];
        }
        const float Av = ws[dbase + kl];
        const float Bv = ws[D + dbase + kl];
        #pragma unroll
        for (int i = 0; i < 4; ++i) {
            const int bl = tg + i * 8;
            const float xv = x[(bbase + bl) * D + dbase + kl];
            float sv, cv;
            sincosf(xv, &sv, &cv);
            Zl[bl * 36 + kl] = part1 + cv * Av + sv * Bv;
        }
        __syncthreads();
        #pragma unroll
        for (int k = 0; k < 32; ++k) {
            const float4 wv = *(const float4*)&Wl[k * 132 + c0];
            float zb[4];
            #pragma unroll
            for (int bj = 0; bj < 4; ++bj) zb[bj] = Zl[(b0 + bj) * 36 + k];
            #pragma unroll
            for (int bj = 0; bj < 4; ++bj) {
                acc[bj][0] += zb[bj] * wv.x;
                acc[bj][1] += zb[bj] * wv.y;
                acc[bj][2] += zb[bj] * wv.z;
                acc[bj][3] += zb[bj] * wv.w;
            }
        }
        __syncthreads();
    }
    if (c0 < NCLS) {
        #pragma unroll
        for (int bj = 0; bj < 4; ++bj) {
            const int row = bbase + b0 + bj;
            #pragma unroll
            for (int q = 0; q < 4; ++q) {
                const int c = c0 + q;
                if (c < NCLS) {
                    float v = acc[bj][q];
                    if (j == 0) v += fcb[c];
                    atomicAdd(&out[row * NCLS + c], v);
                }
            }
        }
    }
}

extern "C" void kernel_launch(void* const* d_in, const int* in_sizes, int n_in,
                              void* d_out, int out_size, void* d_ws, size_t ws_size,
                              hipStream_t stream) {
    const float* x   = (const float*)d_in[0];
    const float* a   = (const float*)d_in[1];
    const float* b   = (const float*)d_in[2];
    const float* w5  = (const float*)d_in[3];
    const float* n5  = (const float*)d_in[4];
    const float* fcw = (const float*)d_in[5];
    const float* fcb = (const float*)d_in[6];
    float* out = (float*)d_out;
    float* wsf = (float*)d_ws;

    hipMemsetAsync(d_ws, 0, 2 * D * sizeof(float), stream);

    if (ws_size >= WS_NEED) {
        unsigned short* Wb = (unsigned short*)((char*)d_ws + WS_OFF_W);
        float*          Pp = (float*)((char*)d_ws + WS_OFF_P);
        prep_kernel<<<dim3(624), 256, 0, stream>>>(a, b, fcw, wsf, Wb);
        fzgemm_kernel<<<dim3(8, KS), 256, 0, stream>>>(x, w5, n5, wsf, Wb, Pp);
        reduce2_kernel<<<dim3(200), 256, 0, stream>>>(Pp, fcb, out);
    } else {
        hipMemsetAsync(d_out, 0, (size_t)out_size * sizeof(float), stream);
        prep_kernel<<<dim3(288), 256, 0, stream>>>(a, b, fcw, wsf,
                                                   (unsigned short*)d_ws /*unused*/);
        fused_gemm_kernel<<<dim3(16, 32), 256, 0, stream>>>(x, w5, n5, fcw, fcb,
                                                            wsf, out);
    }
}

// Round 8
// 126.328 us; speedup vs baseline: 1.0714x; 1.0144x over previous
//
#include <hip/hip_runtime.h>
#include <math.h>

#define D 3072
#define BATCH 512
#define NCLS 100
#define KS 32
#define KCHUNK (D / KS)   // 96
#define RC 96             // row-chunks in colsum (32 rows each)

typedef __attribute__((ext_vector_type(8))) short bf16x8;
typedef __attribute__((ext_vector_type(4))) float f32x4;

// ws byte layout (fast path):
//   0        : pws f32 [2][96][3072]  (per-rowchunk colsum partials) 2359296 B
//   2359296  : Wb bf16 [112][3072]                                    688128 B
//   3047424  : partials bf16 [KS][512][100]                          3276800 B
//   total 6324224 B
#define WS_OFF_W   2359296
#define WS_OFF_P   3047424
#define WS_NEED    (WS_OFF_P + (size_t)KS * BATCH * NCLS * 2)

__device__ inline unsigned short f2bf(float f) {
    unsigned u = __float_as_uint(f);
    u += 0x7FFF + ((u >> 16) & 1);          // round-to-nearest-even
    return (unsigned short)(u >> 16);
}
__device__ inline float bf2f(unsigned short s) {
    return __uint_as_float(((unsigned)s) << 16);
}

// ---------------------------------------------------------------------------
// K1 "prep": two independent jobs, one dispatch, NO atomics, NO pre-zeroing:
//  blocks [0,288):   colsum partials. Block (rc,cg) sums rows rc*32..rc*32+31
//                    for its 1024 columns and STORES pws[0][rc][col] (a) and
//                    pws[1][rc][col] (b). Deterministic float4 stores.
//  blocks [288,624): fc_w fp32 [100][3072] -> bf16 [112][3072] (pad rows 0)
// ---------------------------------------------------------------------------
__global__ __launch_bounds__(256) void prep_kernel(const float* __restrict__ a,
                                                   const float* __restrict__ b,
                                                   const float* __restrict__ fcw,
                                                   float* __restrict__ pws,
                                                   unsigned short* __restrict__ Wb) {
    const int bid = blockIdx.x;
    const int t   = threadIdx.x;
    if (bid < 288) {
        const int rc   = bid / 3;
        const int cg   = bid % 3;
        const int col  = cg * 1024 + t * 4;
        const int row0 = rc * 32;
        float4 sa = make_float4(0.f, 0.f, 0.f, 0.f);
        float4 sb = make_float4(0.f, 0.f, 0.f, 0.f);
        #pragma unroll
        for (int r = 0; r < 32; ++r) {
            const int i = row0 + r;
            const float4 va = *(const float4*)(a + i * D + col);
            const float4 vb = *(const float4*)(b + i * D + col);
            sa.x += va.x; sa.y += va.y; sa.z += va.z; sa.w += va.w;
            sb.x += vb.x; sb.y += vb.y; sb.z += vb.z; sb.w += vb.w;
        }
        *(float4*)(pws + rc * D + col)            = sa;
        *(float4*)(pws + (RC + rc) * D + col)     = sb;
    } else {
        const int idx = (bid - 288) * 256 + t;     // 0..86015
        const int c   = idx / (D / 4);
        const int d   = (idx % (D / 4)) * 4;
        ushort4 o;
        if (c < NCLS) {
            const float4 v = *(const float4*)(fcw + c * D + d);
            o.x = f2bf(v.x); o.y = f2bf(v.y); o.z = f2bf(v.z); o.w = f2bf(v.w);
        } else {
            o.x = o.y = o.z = o.w = 0;
        }
        *(ushort4*)(Wb + c * D + d) = o;
    }
}

// ---------------------------------------------------------------------------
// K2 "fzgemm": fused A/B-reduce + Z-gen + MFMA GEMM, split-K, bf16 partials.
//  Prologue: reduce the 96 rowchunk-partials for this block's 96-col chunk
//            into LDS Al/Bl (L2-hot strided reads, lanes coalesced).
//  Main:     Z = part1 + cos(x)*A + sin(x)*B on the fly into the A-fragment,
//            partial[j] = Z_chunk x Wb^T via 16x16x32 bf16 MFMA.
// Grid (8 m-blocks, KS=32) x 256. A/B frag: lane&15 = row/col, k=(lane>>4)*8+j.
// C/D: col=lane&15, row=(lane>>4)*4+reg  [verified R4].
// ---------------------------------------------------------------------------
__global__ __launch_bounds__(256) void fzgemm_kernel(
        const float* __restrict__ x,
        const float* __restrict__ w5,
        const float* __restrict__ n5,
        const float* __restrict__ pws,              // [2][96][3072] partial colsums
        const unsigned short* __restrict__ Wb,      // [112][3072] bf16
        unsigned short* __restrict__ part) {        // [KS][512][100] bf16
    __shared__ float Al[KCHUNK];
    __shared__ float Bl[KCHUNK];

    const int t    = threadIdx.x;
    const int wave = t >> 6;
    const int lane = t & 63;
    const int l16  = lane & 15;
    const int quad = lane >> 4;
    const int m0   = blockIdx.x * 64 + wave * 16;   // m-tile base (16 rows)
    const int j    = blockIdx.y;                    // k-chunk
    const int cbase = j * KCHUNK;                   // global col base of chunk

    // --- prologue: reduce 96 rowchunk partials for this chunk's columns ---
    if (t < KCHUNK) {                               // waves 0-1: A
        float s = 0.f;
        #pragma unroll 8
        for (int rc = 0; rc < RC; ++rc)
            s += pws[rc * D + cbase + t];
        Al[t] = s;
    } else if (t >= 128 && t < 128 + KCHUNK) {      // waves 2-3: B
        const int c = t - 128;
        float s = 0.f;
        #pragma unroll 8
        for (int rc = 0; rc < RC; ++rc)
            s += pws[(RC + rc) * D + cbase + c];
        Bl[c] = s;
    }

    float part1 = 0.f;
    #pragma unroll
    for (int i = 0; i < 4; ++i)
        part1 += w5[i + 1] * n5[i + 1] + w5[i] * n5[i];

    f32x4 acc[7];
    #pragma unroll
    for (int n = 0; n < 7; ++n) acc[n] = (f32x4){0.f, 0.f, 0.f, 0.f};

    const float* xr = x + (m0 + l16) * D;           // this lane's x row
    __syncthreads();

    #pragma unroll
    for (int kk = 0; kk < KCHUNK; kk += 32) {
        const int lcol = quad * 8 + kk;             // col within chunk
        const int gcol = cbase + lcol;              // global col
        const float4 xv0 = *(const float4*)(xr + gcol);
        const float4 xv1 = *(const float4*)(xr + gcol + 4);
        const float4 Av0 = *(const float4*)&Al[lcol];
        const float4 Av1 = *(const float4*)&Al[lcol + 4];
        const float4 Bv0 = *(const float4*)&Bl[lcol];
        const float4 Bv1 = *(const float4*)&Bl[lcol + 4];

        union { bf16x8 v; unsigned short s[8]; } af;
        float sv, cv;
        __sincosf(xv0.x, &sv, &cv); af.s[0] = f2bf(part1 + cv * Av0.x + sv * Bv0.x);
        __sincosf(xv0.y, &sv, &cv); af.s[1] = f2bf(part1 + cv * Av0.y + sv * Bv0.y);
        __sincosf(xv0.z, &sv, &cv); af.s[2] = f2bf(part1 + cv * Av0.z + sv * Bv0.z);
        __sincosf(xv0.w, &sv, &cv); af.s[3] = f2bf(part1 + cv * Av0.w + sv * Bv0.w);
        __sincosf(xv1.x, &sv, &cv); af.s[4] = f2bf(part1 + cv * Av1.x + sv * Bv1.x);
        __sincosf(xv1.y, &sv, &cv); af.s[5] = f2bf(part1 + cv * Av1.y + sv * Bv1.y);
        __sincosf(xv1.z, &sv, &cv); af.s[6] = f2bf(part1 + cv * Av1.z + sv * Bv1.z);
        __sincosf(xv1.w, &sv, &cv); af.s[7] = f2bf(part1 + cv * Av1.w + sv * Bv1.w);

        #pragma unroll
        for (int n = 0; n < 7; ++n) {
            const bf16x8 bf = *(const bf16x8*)(Wb + (n * 16 + l16) * D + gcol);
            acc[n] = __builtin_amdgcn_mfma_f32_16x16x32_bf16(af.v, bf, acc[n], 0, 0, 0);
        }
    }

    unsigned short* pb = part + (size_t)j * (BATCH * NCLS);
    #pragma unroll
    for (int n = 0; n < 7; ++n) {
        const int c = n * 16 + l16;
        if (c < NCLS) {
            #pragma unroll
            for (int r = 0; r < 4; ++r)
                pb[(m0 + quad * 4 + r) * NCLS + c] = f2bf(acc[n][r]);
        }
    }
}

// ---------------------------------------------------------------------------
// K3: out[b,c] = fcb[c] + sum_ks part[ks][b][c].  2 outputs/thread via uint
// loads (c even). 100 blocks x 256 = 25600 threads x 2 = 51200 outputs.
// ---------------------------------------------------------------------------
__global__ __launch_bounds__(256) void reduce2_kernel(
        const unsigned int* __restrict__ partu,     // [KS][25600] uint (2xbf16)
        const float* __restrict__ fcb,
        float* __restrict__ out) {
    const int idx = blockIdx.x * 256 + threadIdx.x;   // 0..25599
    const int c   = (idx * 2) % NCLS;
    float s0 = fcb[c];
    float s1 = fcb[c + 1];
    #pragma unroll
    for (int ks = 0; ks < KS; ++ks) {
        const unsigned int v = partu[ks * (BATCH * NCLS / 2) + idx];
        s0 += bf2f((unsigned short)(v & 0xFFFF));
        s1 += bf2f((unsigned short)(v >> 16));
    }
    *(float2*)(out + idx * 2) = make_float2(s0, s1);
}

// ---------------------------------------------------------------------------
// Fallback path (insurance if ws_size < WS_NEED): R3's verified kernels.
// ---------------------------------------------------------------------------
__global__ __launch_bounds__(256) void colsum_atomic_kernel(
        const float* __restrict__ a, const float* __restrict__ b,
        float* __restrict__ ws) {
    const int col  = (blockIdx.x % 3) * 1024 + threadIdx.x * 4;
    const int row0 = (blockIdx.x / 3) * 32;
    float4 sa = make_float4(0.f, 0.f, 0.f, 0.f);
    float4 sb = make_float4(0.f, 0.f, 0.f, 0.f);
    #pragma unroll
    for (int r = 0; r < 32; ++r) {
        const float4 va = *(const float4*)(a + (row0 + r) * D + col);
        const float4 vb = *(const float4*)(b + (row0 + r) * D + col);
        sa.x += va.x; sa.y += va.y; sa.z += va.z; sa.w += va.w;
        sb.x += vb.x; sb.y += vb.y; sb.z += vb.z; sb.w += vb.w;
    }
    atomicAdd(&ws[col + 0], sa.x); atomicAdd(&ws[col + 1], sa.y);
    atomicAdd(&ws[col + 2], sa.z); atomicAdd(&ws[col + 3], sa.w);
    atomicAdd(&ws[D + col + 0], sb.x); atomicAdd(&ws[D + col + 1], sb.y);
    atomicAdd(&ws[D + col + 2], sb.z); atomicAdd(&ws[D + col + 3], sb.w);
}

__global__ __launch_bounds__(256) void fused_gemm_kernel(
        const float* __restrict__ x,
        const float* __restrict__ w5,
        const float* __restrict__ n5,
        const float* __restrict__ fcw,
        const float* __restrict__ fcb,
        const float* __restrict__ ws,
        float* __restrict__ out) {
    __shared__ __align__(16) float Zl[32 * 36];
    __shared__ __align__(16) float Wl[32 * 132];
    const int t  = threadIdx.x;
    const int bt = blockIdx.x;
    const int j  = blockIdx.y;
    float part1 = 0.f;
    #pragma unroll
    for (int i = 0; i < 4; ++i)
        part1 += w5[i + 1] * n5[i + 1] + w5[i] * n5[i];
    const int c0 = (t & 31) * 4;
    const int b0 = (t >> 5) * 4;
    const int kl = t & 31;
    const int tg = t >> 5;
    const int bbase = bt * 32;
    float acc[4][4];
    #pragma unroll
    for (int i = 0; i < 4; ++i)
        #pragma unroll
        for (int q = 0; q < 4; ++q) acc[i][q] = 0.f;
    for (int s = 0; s < 3; ++s) {
        const int dbase = j * 96 + s * 32;
        for (int idx = t; idx < NCLS * 32; idx += 256) {
            const int c = idx >> 5;
            const int k = idx & 31;
            Wl[k * 132 + c] = fcw[c * D + dbase + k];
        }
        const float Av = ws[dbase + kl];
        const float Bv = ws[D + dbase + kl];
        #pragma unroll
        for (int i = 0; i < 4; ++i) {
            const int bl = tg + i * 8;
            const float xv = x[(bbase + bl) * D + dbase + kl];
            float sv, cv;
            sincosf(xv, &sv, &cv);
            Zl[bl * 36 + kl] = part1 + cv * Av + sv * Bv;
        }
        __syncthreads();
        #pragma unroll
        for (int k = 0; k < 32; ++k) {
            const float4 wv = *(const float4*)&Wl[k * 132 + c0];
            float zb[4];
            #pragma unroll
            for (int bj = 0; bj < 4; ++bj) zb[bj] = Zl[(b0 + bj) * 36 + k];
            #pragma unroll
            for (int bj = 0; bj < 4; ++bj) {
                acc[bj][0] += zb[bj] * wv.x;
                acc[bj][1] += zb[bj] * wv.y;
                acc[bj][2] += zb[bj] * wv.z;
                acc[bj][3] += zb[bj] * wv.w;
            }
        }
        __syncthreads();
    }
    if (c0 < NCLS) {
        #pragma unroll
        for (int bj = 0; bj < 4; ++bj) {
            const int row = bbase + b0 + bj;
            #pragma unroll
            for (int q = 0; q < 4; ++q) {
                const int c = c0 + q;
                if (c < NCLS) {
                    float v = acc[bj][q];
                    if (j == 0) v += fcb[c];
                    atomicAdd(&out[row * NCLS + c], v);
                }
            }
        }
    }
}

extern "C" void kernel_launch(void* const* d_in, const int* in_sizes, int n_in,
                              void* d_out, int out_size, void* d_ws, size_t ws_size,
                              hipStream_t stream) {
    const float* x   = (const float*)d_in[0];
    const float* a   = (const float*)d_in[1];
    const float* b   = (const float*)d_in[2];
    const float* w5  = (const float*)d_in[3];
    const float* n5  = (const float*)d_in[4];
    const float* fcw = (const float*)d_in[5];
    const float* fcb = (const float*)d_in[6];
    float* out = (float*)d_out;
    float* wsf = (float*)d_ws;

    if (ws_size >= WS_NEED) {
        unsigned short* Wb = (unsigned short*)((char*)d_ws + WS_OFF_W);
        unsigned short* Pp = (unsigned short*)((char*)d_ws + WS_OFF_P);
        prep_kernel<<<dim3(624), 256, 0, stream>>>(a, b, fcw, wsf, Wb);
        fzgemm_kernel<<<dim3(8, KS), 256, 0, stream>>>(x, w5, n5, wsf, Wb, Pp);
        reduce2_kernel<<<dim3(100), 256, 0, stream>>>((const unsigned int*)Pp,
                                                      fcb, out);
    } else {
        hipMemsetAsync(d_ws, 0, 2 * D * sizeof(float), stream);
        hipMemsetAsync(d_out, 0, (size_t)out_size * sizeof(float), stream);
        colsum_atomic_kernel<<<dim3(288), 256, 0, stream>>>(a, b, wsf);
        fused_gemm_kernel<<<dim3(16, 32), 256, 0, stream>>>(x, w5, n5, fcw, fcb,
                                                            wsf, out);
    }
}